// Round 1
// baseline (520.090 us; speedup 1.0000x reference)
//
#include <hip/hip_runtime.h>
#include <math.h>

#define B 64
#define T 2000
#define E 512
#define R 1024
#define A 512
#define M 8

__device__ __forceinline__ float sigmoidf_(float x) { return 1.0f / (1.0f + expf(-x)); }

// ---------------------------------------------------------------------------
// K1: per-batch MLP. One block per batch row b.
//   h = tanh(ahs[b])                (R=1024, LDS)
//   t = h @ W1.T + b1               (A=512,  LDS)   <- NO tanh here
//   x = tanh(t @ W2.T)              (A=512,  LDS)
//   y = x @ Wlin.T + blin           (24)
//   delta=sig(y[8:16]); loc=prev+delta; scale=sig(y[16:24])*2+1; wmix=sig(y[0:8])
// ---------------------------------------------------------------------------
__global__ __launch_bounds__(512) void mlp_kernel(
    const float* __restrict__ ahs, const float* __restrict__ prev_loc,
    const float* __restrict__ W1, const float* __restrict__ b1,
    const float* __restrict__ W2, const float* __restrict__ Wlin,
    const float* __restrict__ blin,
    float* __restrict__ out_loc,    // [B][M]
    float* __restrict__ ws_params)  // [3][B][M]: wmix, loc, scale
{
    __shared__ float sh_h[R];
    __shared__ float sh_t[A];
    __shared__ float sh_x[A];
    __shared__ float sh_y[3 * M];

    const int b = blockIdx.x;
    const int tid = threadIdx.x;

    // h = tanh(ahs[b, :])
    for (int k = tid; k < R; k += 512) sh_h[k] = tanhf(ahs[b * R + k]);
    __syncthreads();

    // t[j] = sum_k h[k] * W1[j,k] + b1[j]   (one output per thread)
    {
        const int j = tid;
        const float4* w4 = (const float4*)(W1 + (size_t)j * R);
        const float4* h4 = (const float4*)sh_h;
        float acc = 0.f;
#pragma unroll 4
        for (int k4 = 0; k4 < R / 4; ++k4) {
            float4 a = h4[k4];
            float4 w = w4[k4];
            acc += a.x * w.x + a.y * w.y + a.z * w.z + a.w * w.w;
        }
        sh_t[j] = acc + b1[j];
    }
    __syncthreads();

    // x[j] = tanh( sum_k t[k] * W2[j,k] )
    {
        const int j = tid;
        const float4* w4 = (const float4*)(W2 + (size_t)j * A);
        const float4* t4 = (const float4*)sh_t;
        float acc = 0.f;
#pragma unroll 4
        for (int k4 = 0; k4 < A / 4; ++k4) {
            float4 a = t4[k4];
            float4 w = w4[k4];
            acc += a.x * w.x + a.y * w.y + a.z * w.z + a.w * w.w;
        }
        sh_x[j] = tanhf(acc);
    }
    __syncthreads();

    // y[i] = sum_k x[k] * Wlin[i,k] + blin[i], 24 outputs, 16 threads each
    if (tid < 16 * 3 * M) {
        const int i = tid >> 4;
        const int lane = tid & 15;
        float s = 0.f;
        for (int k = lane; k < A; k += 16) s += sh_x[k] * Wlin[i * A + k];
        s += __shfl_down(s, 8, 16);
        s += __shfl_down(s, 4, 16);
        s += __shfl_down(s, 2, 16);
        s += __shfl_down(s, 1, 16);
        if (lane == 0) sh_y[i] = s + blin[i];
    }
    __syncthreads();

    if (tid < M) {
        const int m = tid;
        const float wv = sh_y[m];
        const float dv = sh_y[M + m];
        const float sv = sh_y[2 * M + m];
        const float delta = sigmoidf_(dv);
        const float loc = prev_loc[b * M + m] + delta;
        const float scale = sigmoidf_(sv) * 2.0f + 1.0f;
        const float wmix = sigmoidf_(wv);
        out_loc[b * M + m] = loc;
        ws_params[0 * B * M + b * M + m] = wmix;
        ws_params[1 * B * M + b * M + m] = loc;
        ws_params[2 * B * M + b * M + m] = scale;
    }
}

// ---------------------------------------------------------------------------
// K2: alignment + softmax per batch row. One block per b, 256 threads,
// each thread owns 8 t-positions (2000 = 7*256 + 208).
// ---------------------------------------------------------------------------
__global__ __launch_bounds__(256) void align_softmax_kernel(
    const unsigned char* __restrict__ mask,
    const float* __restrict__ ws_params,
    float* __restrict__ out_w)  // [B][T]
{
    __shared__ float sh_wmix[M], sh_loc[M], sh_scale[M];
    __shared__ float sred[4];
    __shared__ float sbval;

    const int b = blockIdx.x;
    const int tid = threadIdx.x;

    if (tid < M) {
        sh_wmix[tid]  = ws_params[0 * B * M + b * M + tid];
        sh_loc[tid]   = ws_params[1 * B * M + b * M + tid];
        sh_scale[tid] = ws_params[2 * B * M + b * M + tid];
    }
    __syncthreads();

    float a[8];
    float lmax = -1e30f;
#pragma unroll
    for (int i = 0; i < 8; ++i) {
        const int t = tid + i * 256;
        float v = 0.f;
        if (t < T) {
            const float tf = (float)t;
#pragma unroll
            for (int m = 0; m < M; ++m) {
                const float d = sh_loc[m] - tf;
                const float s = sh_scale[m];
                const float z = 0.5f * (erff((d + 0.5f) * s) - erff((d - 0.5f) * s));
                v += z * sh_wmix[m];
            }
            if (mask[b * T + t]) v = 0.f;
            lmax = fmaxf(lmax, v);
        }
        a[i] = v;
    }

    // block max
    for (int off = 32; off > 0; off >>= 1) lmax = fmaxf(lmax, __shfl_down(lmax, off));
    if ((tid & 63) == 0) sred[tid >> 6] = lmax;
    __syncthreads();
    if (tid == 0) sbval = fmaxf(fmaxf(sred[0], sred[1]), fmaxf(sred[2], sred[3]));
    __syncthreads();
    const float bmax = sbval;

    float lsum = 0.f;
#pragma unroll
    for (int i = 0; i < 8; ++i) {
        const int t = tid + i * 256;
        if (t < T) {
            a[i] = expf(a[i] - bmax);
            lsum += a[i];
        }
    }
    for (int off = 32; off > 0; off >>= 1) lsum += __shfl_down(lsum, off);
    if ((tid & 63) == 0) sred[tid >> 6] = lsum;
    __syncthreads();
    if (tid == 0) sbval = sred[0] + sred[1] + sred[2] + sred[3];
    __syncthreads();
    const float inv = 1.0f / sbval;

#pragma unroll
    for (int i = 0; i < 8; ++i) {
        const int t = tid + i * 256;
        if (t < T) out_w[b * T + t] = a[i] * inv;
    }
}

// ---------------------------------------------------------------------------
// K3: context = sum_t w[b,t] * memory[b,t,:]. Grid (B, 8 t-chunks of 250).
// 256 threads: e4 = tid&127 covers E=512 as float4, tp = tid>>7 splits t.
// Partial sums atomicAdd'ed into zero-initialized out_ctx.
// ---------------------------------------------------------------------------
#define TCH 250
__global__ __launch_bounds__(256) void context_kernel(
    const float* __restrict__ memory,
    const float* __restrict__ w,      // [B][T]
    float* __restrict__ out_ctx)      // [B][E], pre-zeroed
{
    __shared__ float sh_w[TCH];
    const int b = blockIdx.x;
    const int chunk = blockIdx.y;
    const int tid = threadIdx.x;
    const int t0 = chunk * TCH;

    for (int i = tid; i < TCH; i += 256) sh_w[i] = w[b * T + t0 + i];
    __syncthreads();

    const int e4 = tid & 127;
    const int tp = tid >> 7;
    const float4* mem4 = (const float4*)(memory + (size_t)(b * T + t0) * E);

    float4 acc = {0.f, 0.f, 0.f, 0.f};
    for (int t = tp; t < TCH; t += 2) {
        const float wv = sh_w[t];  // broadcast within wave
        const float4 mv = mem4[(size_t)t * (E / 4) + e4];
        acc.x += wv * mv.x;
        acc.y += wv * mv.y;
        acc.z += wv * mv.z;
        acc.w += wv * mv.w;
    }

    float* dst = out_ctx + b * E + e4 * 4;
    atomicAdd(dst + 0, acc.x);
    atomicAdd(dst + 1, acc.y);
    atomicAdd(dst + 2, acc.z);
    atomicAdd(dst + 3, acc.w);
}

extern "C" void kernel_launch(void* const* d_in, const int* in_sizes, int n_in,
                              void* d_out, int out_size, void* d_ws, size_t ws_size,
                              hipStream_t stream) {
    const float* ahs      = (const float*)d_in[0];
    const float* memory   = (const float*)d_in[1];
    const float* prev_loc = (const float*)d_in[2];
    const unsigned char* mask = (const unsigned char*)d_in[3];
    const float* W1   = (const float*)d_in[4];
    const float* b1   = (const float*)d_in[5];
    const float* W2   = (const float*)d_in[6];
    const float* Wlin = (const float*)d_in[7];
    const float* blin = (const float*)d_in[8];

    float* out = (float*)d_out;
    float* out_ctx = out;                    // [B][E]
    float* out_w   = out + B * E;            // [B][T]
    float* out_loc = out + B * E + B * T;    // [B][M]
    float* ws = (float*)d_ws;                // 3*B*M floats of params

    hipMemsetAsync(out_ctx, 0, (size_t)B * E * sizeof(float), stream);

    mlp_kernel<<<dim3(B), dim3(512), 0, stream>>>(
        ahs, prev_loc, W1, b1, W2, Wlin, blin, out_loc, ws);

    align_softmax_kernel<<<dim3(B), dim3(256), 0, stream>>>(mask, ws, out_w);

    context_kernel<<<dim3(B, 8), dim3(256), 0, stream>>>(memory, out_w, out_ctx);
}

// Round 2
// 478.605 us; speedup vs baseline: 1.0867x; 1.0867x over previous
//
#include <hip/hip_runtime.h>
#include <math.h>

#define B 64
#define T 2000
#define E 512
#define R 1024
#define A 512
#define M 8

#define NCH 16          // t-chunks for context kernel
#define TCH (T / NCH)   // 125

__device__ __forceinline__ float sigmoidf_(float x) { return 1.0f / (1.0f + expf(-x)); }

// ---------------------------------------------------------------------------
// K12: fused per-batch MLP + alignment + softmax. One block per batch row.
//   h = tanh(ahs[b]); t = h@W1.T+b1; x = tanh(t@W2.T); y = x@Wlin.T+blin
//   params -> alignment (erf mixture) -> softmax -> out_w; also out_loc.
// ---------------------------------------------------------------------------
__global__ __launch_bounds__(512) void mlp_align_kernel(
    const float* __restrict__ ahs, const float* __restrict__ prev_loc,
    const unsigned char* __restrict__ mask,
    const float* __restrict__ W1, const float* __restrict__ b1,
    const float* __restrict__ W2, const float* __restrict__ Wlin,
    const float* __restrict__ blin,
    float* __restrict__ out_w,    // [B][T]
    float* __restrict__ out_loc)  // [B][M]
{
    __shared__ float sh_h[R];
    __shared__ float sh_t[A];
    __shared__ float sh_x[A];
    __shared__ float sh_y[3 * M];
    __shared__ float sh_wmix[M], sh_loc[M], sh_scale[M];
    __shared__ float sred[8];
    __shared__ float sbval;

    const int b = blockIdx.x;
    const int tid = threadIdx.x;

    // h = tanh(ahs[b, :])
    for (int k = tid; k < R; k += 512) sh_h[k] = tanhf(ahs[b * R + k]);
    __syncthreads();

    // t[j] = h . W1[j,:] + b1[j]  (one output per thread; 4 accumulators)
    {
        const int j = tid;
        const float4* w4 = (const float4*)(W1 + (size_t)j * R);
        const float4* h4 = (const float4*)sh_h;
        float a0 = 0.f, a1 = 0.f, a2 = 0.f, a3 = 0.f;
#pragma unroll 4
        for (int k4 = 0; k4 < R / 4; k4 += 4) {
            float4 x0 = h4[k4 + 0], w0 = w4[k4 + 0];
            float4 x1 = h4[k4 + 1], w1 = w4[k4 + 1];
            float4 x2 = h4[k4 + 2], w2 = w4[k4 + 2];
            float4 x3 = h4[k4 + 3], w3 = w4[k4 + 3];
            a0 += x0.x * w0.x + x0.y * w0.y + x0.z * w0.z + x0.w * w0.w;
            a1 += x1.x * w1.x + x1.y * w1.y + x1.z * w1.z + x1.w * w1.w;
            a2 += x2.x * w2.x + x2.y * w2.y + x2.z * w2.z + x2.w * w2.w;
            a3 += x3.x * w3.x + x3.y * w3.y + x3.z * w3.z + x3.w * w3.w;
        }
        sh_t[j] = (a0 + a1) + (a2 + a3) + b1[j];
    }
    __syncthreads();

    // x[j] = tanh( t . W2[j,:] )
    {
        const int j = tid;
        const float4* w4 = (const float4*)(W2 + (size_t)j * A);
        const float4* t4 = (const float4*)sh_t;
        float a0 = 0.f, a1 = 0.f, a2 = 0.f, a3 = 0.f;
#pragma unroll 4
        for (int k4 = 0; k4 < A / 4; k4 += 4) {
            float4 x0 = t4[k4 + 0], w0 = w4[k4 + 0];
            float4 x1 = t4[k4 + 1], w1 = w4[k4 + 1];
            float4 x2 = t4[k4 + 2], w2 = w4[k4 + 2];
            float4 x3 = t4[k4 + 3], w3 = w4[k4 + 3];
            a0 += x0.x * w0.x + x0.y * w0.y + x0.z * w0.z + x0.w * w0.w;
            a1 += x1.x * w1.x + x1.y * w1.y + x1.z * w1.z + x1.w * w1.w;
            a2 += x2.x * w2.x + x2.y * w2.y + x2.z * w2.z + x2.w * w2.w;
            a3 += x3.x * w3.x + x3.y * w3.y + x3.z * w3.z + x3.w * w3.w;
        }
        sh_x[j] = tanhf((a0 + a1) + (a2 + a3));
    }
    __syncthreads();

    // y[i] = x . Wlin[i,:] + blin[i], 24 outputs, 16 threads each
    if (tid < 16 * 3 * M) {
        const int i = tid >> 4;
        const int lane = tid & 15;
        float s = 0.f;
        for (int k = lane; k < A; k += 16) s += sh_x[k] * Wlin[i * A + k];
        s += __shfl_down(s, 8, 16);
        s += __shfl_down(s, 4, 16);
        s += __shfl_down(s, 2, 16);
        s += __shfl_down(s, 1, 16);
        if (lane == 0) sh_y[i] = s + blin[i];
    }
    __syncthreads();

    if (tid < M) {
        const int m = tid;
        const float delta = sigmoidf_(sh_y[M + m]);
        const float loc = prev_loc[b * M + m] + delta;
        sh_wmix[m]  = sigmoidf_(sh_y[m]);
        sh_loc[m]   = loc;
        sh_scale[m] = sigmoidf_(sh_y[2 * M + m]) * 2.0f + 1.0f;
        out_loc[b * M + m] = loc;
    }
    __syncthreads();

    // alignment: a[t] = sum_m wmix[m] * 0.5*(erf((d+.5)*s) - erf((d-.5)*s))
    float a[4];
    float lmax = -1e30f;
#pragma unroll
    for (int i = 0; i < 4; ++i) {
        const int t = tid + i * 512;
        float v = 0.f;
        if (t < T) {
            const float tf = (float)t;
#pragma unroll
            for (int m = 0; m < M; ++m) {
                const float d = sh_loc[m] - tf;
                const float s = sh_scale[m];
                v += 0.5f * (erff((d + 0.5f) * s) - erff((d - 0.5f) * s)) * sh_wmix[m];
            }
            if (mask[b * T + t]) v = 0.f;
            lmax = fmaxf(lmax, v);
        }
        a[i] = v;
    }

    // block max over 8 waves
    for (int off = 32; off > 0; off >>= 1) lmax = fmaxf(lmax, __shfl_down(lmax, off));
    if ((tid & 63) == 0) sred[tid >> 6] = lmax;
    __syncthreads();
    if (tid == 0) {
        float m0 = sred[0];
        for (int i = 1; i < 8; ++i) m0 = fmaxf(m0, sred[i]);
        sbval = m0;
    }
    __syncthreads();
    const float bmax = sbval;

    float lsum = 0.f;
#pragma unroll
    for (int i = 0; i < 4; ++i) {
        const int t = tid + i * 512;
        if (t < T) {
            a[i] = expf(a[i] - bmax);
            lsum += a[i];
        }
    }
    for (int off = 32; off > 0; off >>= 1) lsum += __shfl_down(lsum, off);
    if ((tid & 63) == 0) sred[tid >> 6] = lsum;
    __syncthreads();
    if (tid == 0) {
        float s0 = 0.f;
        for (int i = 0; i < 8; ++i) s0 += sred[i];
        sbval = s0;
    }
    __syncthreads();
    const float inv = 1.0f / sbval;

#pragma unroll
    for (int i = 0; i < 4; ++i) {
        const int t = tid + i * 512;
        if (t < T) out_w[b * T + t] = a[i] * inv;
    }
}

// ---------------------------------------------------------------------------
// K3: per-chunk partial context. Grid (B, NCH), 512 threads.
// e4 = tid&127 covers E as float4; tp = tid>>7 gives 4 t-streams.
// Block-level LDS reduce across tp; partial written non-atomically to ws.
// ---------------------------------------------------------------------------
__global__ __launch_bounds__(512) void context_partial_kernel(
    const float* __restrict__ memory,
    const float* __restrict__ w,         // [B][T]
    float* __restrict__ partials)        // [B][NCH][E]
{
    __shared__ float sh_w[TCH];
    __shared__ float4 sh_acc[512];

    const int b = blockIdx.x;
    const int chunk = blockIdx.y;
    const int tid = threadIdx.x;
    const int t0 = chunk * TCH;

    if (tid < TCH) sh_w[tid] = w[b * T + t0 + tid];
    __syncthreads();

    const int e4 = tid & 127;
    const int tp = tid >> 7;  // 0..3
    const float4* mem4 = (const float4*)(memory + (size_t)(b * T + t0) * E);

    float4 acc = {0.f, 0.f, 0.f, 0.f};
#pragma unroll 4
    for (int t = tp; t < TCH; t += 4) {
        const float wv = sh_w[t];
        const float4 mv = mem4[(size_t)t * (E / 4) + e4];
        acc.x += wv * mv.x;
        acc.y += wv * mv.y;
        acc.z += wv * mv.z;
        acc.w += wv * mv.w;
    }
    sh_acc[tid] = acc;
    __syncthreads();

    if (tid < 128) {
        const float4 a0 = sh_acc[tid];
        const float4 a1 = sh_acc[tid + 128];
        const float4 a2 = sh_acc[tid + 256];
        const float4 a3 = sh_acc[tid + 384];
        float4 r;
        r.x = (a0.x + a1.x) + (a2.x + a3.x);
        r.y = (a0.y + a1.y) + (a2.y + a3.y);
        r.z = (a0.z + a1.z) + (a2.z + a3.z);
        r.w = (a0.w + a1.w) + (a2.w + a3.w);
        float4* dst = (float4*)(partials + ((size_t)b * NCH + chunk) * E);
        dst[tid] = r;
    }
}

// ---------------------------------------------------------------------------
// K4: reduce NCH partials -> out_ctx [B][E]. 32768 threads total.
// ---------------------------------------------------------------------------
__global__ __launch_bounds__(256) void context_reduce_kernel(
    const float* __restrict__ partials,  // [B][NCH][E]
    float* __restrict__ out_ctx)         // [B][E]
{
    const int idx = blockIdx.x * 256 + threadIdx.x;  // < B*E
    const int b = idx >> 9;        // /E
    const int e = idx & (E - 1);
    float s = 0.f;
#pragma unroll
    for (int c = 0; c < NCH; ++c) s += partials[((size_t)b * NCH + c) * E + e];
    out_ctx[idx] = s;
}

extern "C" void kernel_launch(void* const* d_in, const int* in_sizes, int n_in,
                              void* d_out, int out_size, void* d_ws, size_t ws_size,
                              hipStream_t stream) {
    const float* ahs      = (const float*)d_in[0];
    const float* memory   = (const float*)d_in[1];
    const float* prev_loc = (const float*)d_in[2];
    const unsigned char* mask = (const unsigned char*)d_in[3];
    const float* W1   = (const float*)d_in[4];
    const float* b1   = (const float*)d_in[5];
    const float* W2   = (const float*)d_in[6];
    const float* Wlin = (const float*)d_in[7];
    const float* blin = (const float*)d_in[8];

    float* out = (float*)d_out;
    float* out_ctx = out;                    // [B][E]
    float* out_w   = out + B * E;            // [B][T]
    float* out_loc = out + B * E + B * T;    // [B][M]
    float* partials = (float*)d_ws;          // [B][NCH][E] = 2 MB

    mlp_align_kernel<<<dim3(B), dim3(512), 0, stream>>>(
        ahs, prev_loc, mask, W1, b1, W2, Wlin, blin, out_w, out_loc);

    context_partial_kernel<<<dim3(B, NCH), dim3(512), 0, stream>>>(
        memory, out_w, partials);

    context_reduce_kernel<<<dim3((B * E) / 256), dim3(256), 0, stream>>>(
        partials, out_ctx);
}

// Round 4
// 434.271 us; speedup vs baseline: 1.1976x; 1.1021x over previous
//
#include <hip/hip_runtime.h>
#include <math.h>

#define B 64
#define T 2000
#define E 512
#define R 1024
#define A 512
#define M 8

#define NCH 16          // t-chunks for context kernel
#define TCH (T / NCH)   // 125
#define NP  (NCH * 4)   // partials per batch (4 tp-groups per chunk)

typedef float nfloat4 __attribute__((ext_vector_type(4)));  // native vec for nontemporal builtin

__device__ __forceinline__ float sigmoidf_(float x) { return 1.0f / (1.0f + expf(-x)); }
__device__ __forceinline__ float dot4_(float4 a, float4 b) {
    return (a.x * b.x + a.y * b.y) + (a.z * b.z + a.w * b.w);
}

// ---------------------------------------------------------------------------
// K12: fused per-batch MLP + alignment + softmax. One block (512 thr) per b.
// Layers 1/2 use wave-per-output GEMV: lanes span k (coalesced weight rows),
// activations held in registers, shuffle-reduce per output.
// ---------------------------------------------------------------------------
__global__ __launch_bounds__(512) void mlp_align_kernel(
    const float* __restrict__ ahs, const float* __restrict__ prev_loc,
    const unsigned char* __restrict__ mask,
    const float* __restrict__ W1, const float* __restrict__ b1,
    const float* __restrict__ W2, const float* __restrict__ Wlin,
    const float* __restrict__ blin,
    float* __restrict__ out_w,    // [B][T]
    float* __restrict__ out_loc)  // [B][M]
{
    __shared__ float sh_h[R];
    __shared__ float sh_t[A];
    __shared__ float sh_x[A];
    __shared__ float sh_y[3 * M];
    __shared__ float sh_wmix[M], sh_loc[M], sh_scale[M];
    __shared__ float sred[8];
    __shared__ float sbval;

    const int b = blockIdx.x;
    const int tid = threadIdx.x;
    const int wave = tid >> 6;
    const int lane = tid & 63;

    // h = tanh(ahs[b, :])
    for (int k = tid; k < R; k += 512) sh_h[k] = tanhf(ahs[b * R + k]);
    __syncthreads();

    // ---- layer 1: t[j] = h . W1[j,:] + b1[j]; wave handles j in [64w,64w+64)
    {
        const float4* h4 = (const float4*)sh_h;
        const float4 h0 = h4[lane], h1 = h4[lane + 64],
                     h2 = h4[lane + 128], h3 = h4[lane + 192];
        for (int j = 0; j < 64; j += 2) {
            const int ja = wave * 64 + j;
            const int jb = ja + 1;
            const float4* ra = (const float4*)(W1 + (size_t)ja * R);
            const float4* rb = (const float4*)(W1 + (size_t)jb * R);
            float4 a0 = ra[lane], a1 = ra[lane + 64], a2 = ra[lane + 128], a3 = ra[lane + 192];
            float4 c0 = rb[lane], c1 = rb[lane + 64], c2 = rb[lane + 128], c3 = rb[lane + 192];
            float accA = (dot4_(h0, a0) + dot4_(h1, a1)) + (dot4_(h2, a2) + dot4_(h3, a3));
            float accB = (dot4_(h0, c0) + dot4_(h1, c1)) + (dot4_(h2, c2) + dot4_(h3, c3));
#pragma unroll
            for (int off = 32; off > 0; off >>= 1) {
                accA += __shfl_down(accA, off);
                accB += __shfl_down(accB, off);
            }
            if (lane == 0) {
                sh_t[ja] = accA + b1[ja];
                sh_t[jb] = accB + b1[jb];
            }
        }
    }
    __syncthreads();

    // ---- layer 2: x[j] = tanh( t . W2[j,:] )
    {
        const float4* t4 = (const float4*)sh_t;
        const float4 t0 = t4[lane], t1 = t4[lane + 64];
        for (int j = 0; j < 64; j += 2) {
            const int ja = wave * 64 + j;
            const int jb = ja + 1;
            const float4* ra = (const float4*)(W2 + (size_t)ja * A);
            const float4* rb = (const float4*)(W2 + (size_t)jb * A);
            float4 a0 = ra[lane], a1 = ra[lane + 64];
            float4 c0 = rb[lane], c1 = rb[lane + 64];
            float accA = dot4_(t0, a0) + dot4_(t1, a1);
            float accB = dot4_(t0, c0) + dot4_(t1, c1);
#pragma unroll
            for (int off = 32; off > 0; off >>= 1) {
                accA += __shfl_down(accA, off);
                accB += __shfl_down(accB, off);
            }
            if (lane == 0) {
                sh_x[ja] = tanhf(accA);
                sh_x[jb] = tanhf(accB);
            }
        }
    }
    __syncthreads();

    // ---- head: y[i] = x . Wlin[i,:] + blin[i], 24 outputs, 16 threads each
    if (tid < 16 * 3 * M) {
        const int i = tid >> 4;
        const int l16 = tid & 15;
        float s = 0.f;
        for (int k = l16; k < A; k += 16) s += sh_x[k] * Wlin[i * A + k];
        s += __shfl_down(s, 8, 16);
        s += __shfl_down(s, 4, 16);
        s += __shfl_down(s, 2, 16);
        s += __shfl_down(s, 1, 16);
        if (l16 == 0) sh_y[i] = s + blin[i];
    }
    __syncthreads();

    if (tid < M) {
        const int m = tid;
        const float delta = sigmoidf_(sh_y[M + m]);
        const float loc = prev_loc[b * M + m] + delta;
        sh_wmix[m]  = sigmoidf_(sh_y[m]);
        sh_loc[m]   = loc;
        sh_scale[m] = sigmoidf_(sh_y[2 * M + m]) * 2.0f + 1.0f;
        out_loc[b * M + m] = loc;
    }
    __syncthreads();

    // ---- alignment. Note: a[t] in [0, M) since z>=0, wmix<1, so exp(a) is
    // safe without max-subtraction (softmax invariant to the shift).
    float a[4];
    float lsum = 0.f;
#pragma unroll
    for (int i = 0; i < 4; ++i) {
        const int t = tid + i * 512;
        if (t < T) {
            const float tf = (float)t;
            float v = 0.f;
#pragma unroll
            for (int m = 0; m < M; ++m) {
                const float d = sh_loc[m] - tf;
                const float s = sh_scale[m];
                v += 0.5f * (erff((d + 0.5f) * s) - erff((d - 0.5f) * s)) * sh_wmix[m];
            }
            if (mask[b * T + t]) v = 0.f;
            a[i] = expf(v);
            lsum += a[i];
        } else {
            a[i] = 0.f;
        }
    }
#pragma unroll
    for (int off = 32; off > 0; off >>= 1) lsum += __shfl_down(lsum, off);
    if (lane == 0) sred[wave] = lsum;
    __syncthreads();
    if (tid == 0) {
        float s0 = 0.f;
        for (int i = 0; i < 8; ++i) s0 += sred[i];
        sbval = s0;
    }
    __syncthreads();
    const float inv = 1.0f / sbval;

#pragma unroll
    for (int i = 0; i < 4; ++i) {
        const int t = tid + i * 512;
        if (t < T) out_w[b * T + t] = a[i] * inv;
    }
}

// ---------------------------------------------------------------------------
// K3: per-chunk partial context. Grid (B, NCH), 512 threads.
// e4 = tid&127 covers E as float4; tp = tid>>7 gives 4 t-streams, each
// writing its own partial (no in-block reduction, no second barrier).
// memory is streamed read-once -> nontemporal loads.
// ---------------------------------------------------------------------------
__global__ __launch_bounds__(512) void context_partial_kernel(
    const float* __restrict__ memory,
    const float* __restrict__ w,         // [B][T]
    float* __restrict__ partials)        // [B][NCH][4][E]
{
    __shared__ float sh_w[TCH];

    const int b = blockIdx.x;
    const int chunk = blockIdx.y;
    const int tid = threadIdx.x;
    const int t0 = chunk * TCH;

    if (tid < TCH) sh_w[tid] = w[b * T + t0 + tid];
    __syncthreads();

    const int e4 = tid & 127;
    const int tp = tid >> 7;  // 0..3
    const nfloat4* mem4 = (const nfloat4*)(memory + (size_t)(b * T + t0) * E);

    float acc0 = 0.f, acc1 = 0.f, acc2 = 0.f, acc3 = 0.f;
#pragma unroll 4
    for (int t = tp; t < TCH; t += 4) {
        const float wv = sh_w[t];
        const nfloat4 mv = __builtin_nontemporal_load(&mem4[(size_t)t * (E / 4) + e4]);
        acc0 += wv * mv.x;
        acc1 += wv * mv.y;
        acc2 += wv * mv.z;
        acc3 += wv * mv.w;
    }

    nfloat4 accv = {acc0, acc1, acc2, acc3};
    nfloat4* dst = (nfloat4*)(partials + (((size_t)b * NCH + chunk) * 4 + tp) * E);
    dst[e4] = accv;
}

// ---------------------------------------------------------------------------
// K4: reduce NP=64 partials -> out_ctx [B][E]. float4-vectorized.
// ---------------------------------------------------------------------------
__global__ __launch_bounds__(256) void context_reduce_kernel(
    const float* __restrict__ partials,  // [B][NP][E]
    float* __restrict__ out_ctx)         // [B][E]
{
    const int idx = blockIdx.x * 256 + threadIdx.x;  // < B*E/4
    const int b = idx >> 7;              // / (E/4)
    const int e4 = idx & 127;
    const float4* p = (const float4*)partials + (size_t)b * NP * (E / 4) + e4;
    float4 s = {0.f, 0.f, 0.f, 0.f};
#pragma unroll 8
    for (int c = 0; c < NP; ++c) {
        const float4 v = p[(size_t)c * (E / 4)];
        s.x += v.x; s.y += v.y; s.z += v.z; s.w += v.w;
    }
    ((float4*)out_ctx)[idx] = s;
}

extern "C" void kernel_launch(void* const* d_in, const int* in_sizes, int n_in,
                              void* d_out, int out_size, void* d_ws, size_t ws_size,
                              hipStream_t stream) {
    const float* ahs      = (const float*)d_in[0];
    const float* memory   = (const float*)d_in[1];
    const float* prev_loc = (const float*)d_in[2];
    const unsigned char* mask = (const unsigned char*)d_in[3];
    const float* W1   = (const float*)d_in[4];
    const float* b1   = (const float*)d_in[5];
    const float* W2   = (const float*)d_in[6];
    const float* Wlin = (const float*)d_in[7];
    const float* blin = (const float*)d_in[8];

    float* out = (float*)d_out;
    float* out_ctx = out;                    // [B][E]
    float* out_w   = out + B * E;            // [B][T]
    float* out_loc = out + B * E + B * T;    // [B][M]
    float* partials = (float*)d_ws;          // [B][NP][E] = 8 MB

    mlp_align_kernel<<<dim3(B), dim3(512), 0, stream>>>(
        ahs, prev_loc, mask, W1, b1, W2, Wlin, blin, out_w, out_loc);

    context_partial_kernel<<<dim3(B, NCH), dim3(512), 0, stream>>>(
        memory, out_w, partials);

    context_reduce_kernel<<<dim3((B * E / 4) / 256), dim3(256), 0, stream>>>(
        partials, out_ctx);
}